// Round 6
// baseline (245.668 us; speedup 1.0000x reference)
//
#include <hip/hip_runtime.h>

// QWTForward: reference "filtering" is exactly x * sum(h), downsample is
// linear, so each of the 16 output blocks is (S_A*S_B) * D where
// D = bicubic-downsample(image). One fused memory-bound kernel:
//   read 50 MB image, compute D, write 16 scaled copies (201 MB).
//
// R1/R2 changes vs 241.4us baseline:
//  - nontemporal stores (via native vector type; HIP float4 class is
//    rejected by the builtin): 201 MB streaming output no longer thrashes
//    L2, so vertically-reused image rows stay resident.
//  - 2 output rows per thread: 6 input rows instead of 8 per 2 output rows.

#define BW0 -0.09375f
#define BW1  0.59375f
#define BW2  0.59375f
#define BW3 -0.09375f

#define H_IN  512
#define W_IN  512
#define H_OUT 256
#define W_OUT 256
#define PLANE_OUT (H_OUT * W_OUT)          // 65536
#define TENSOR_STRIDE (16 * 12 * PLANE_OUT) // floats per out tensor

typedef __attribute__((ext_vector_type(4))) float f32x4;

__global__ __launch_bounds__(256) void qwt_fused_kernel(
    const float* __restrict__ img,
    const float* __restrict__ gl, const float* __restrict__ gh,
    const float* __restrict__ fl, const float* __restrict__ fh,
    float* __restrict__ out)
{
    __shared__ float s_scale[16];

    const int tid = threadIdx.x;

    // ---- wave 0: filter sums + 16 scale products -> LDS ----
    if (tid < 64) {
        float vgl = 0.f, vgh = 0.f, vfl = 0.f, vfh = 0.f;
        if (tid < 30) { vgl = gl[tid]; vgh = gh[tid]; vfl = fl[tid]; vfh = fh[tid]; }
        #pragma unroll
        for (int m = 32; m >= 1; m >>= 1) {
            vgl += __shfl_xor(vgl, m);
            vgh += __shfl_xor(vgh, m);
            vfl += __shfl_xor(vfl, m);
            vfh += __shfl_xor(vfh, m);
        }
        if (tid < 16) {
            const int t = tid >> 2, cb = tid & 3;
            // A: first-level downsampled tensor (gl_d/fl_d for t<2, gh_d/fh_d for t>=2)
            const float A = (t < 2) ? ((cb & 1) ? vfl : vgl)
                                    : ((cb & 1) ? vfh : vgh);
            // B: second-level filter (g* for cb<2, f* for cb>=2; l for even t, h for odd t)
            const float B = (t & 1) ? ((cb < 2) ? vgh : vfh)
                                    : ((cb < 2) ? vgl : vfl);
            s_scale[tid] = A * B;
        }
    }
    __syncthreads();

    float sc[16];
    #pragma unroll
    for (int i = 0; i < 16; ++i) sc[i] = s_scale[i];

    // ---- each thread: 2 output rows x 4 cols of D = downsample(image) ----
    // idx -> (bc, hp, w4): 64 w-groups x 128 row-pairs x 48 planes = 393216 threads
    const int idx = blockIdx.x * 256 + tid;
    const int w4 = idx & 63;
    const int hp = (idx >> 6) & 127;     // output row pair: rows 2hp, 2hp+1
    const int bc = idx >> 13;            // b*3 + c, 0..47
    const int c  = bc % 3;
    const int b  = bc / 3;

    const float* plane = img + (size_t)bc * (H_IN * W_IN);

    // 6 clamped source rows: 4hp-1 .. 4hp+4 (rows 2..3 shared by both out rows)
    int r[6];
    #pragma unroll
    for (int i = 0; i < 6; ++i) {
        int rr = 4 * hp - 1 + i;
        r[i] = rr < 0 ? 0 : (rr > H_IN - 1 ? H_IN - 1 : rr);
    }

    const int cbase = w4 * 8;            // cols 8w..8w+7 always in-bounds
    int clo = cbase - 1; if (clo < 0) clo = 0;
    int chi = cbase + 8; if (chi > W_IN - 1) chi = W_IN - 1;

    float hv[6][4];
    #pragma unroll
    for (int i = 0; i < 6; ++i) {
        const float* rowp = plane + (size_t)r[i] * W_IN;
        const float4 a  = *(const float4*)(rowp + cbase);
        const float4 b4 = *(const float4*)(rowp + cbase + 4);
        const float v0 = rowp[clo];
        const float v9 = rowp[chi];
        const float v1 = a.x,  v2 = a.y,  v3 = a.z,  v4 = a.w;
        const float v5 = b4.x, v6 = b4.y, v7 = b4.z, v8 = b4.w;
        hv[i][0] = BW0 * v0 + BW1 * v1 + BW2 * v2 + BW3 * v3;
        hv[i][1] = BW0 * v2 + BW1 * v3 + BW2 * v4 + BW3 * v5;
        hv[i][2] = BW0 * v4 + BW1 * v5 + BW2 * v6 + BW3 * v7;
        hv[i][3] = BW0 * v6 + BW1 * v7 + BW2 * v8 + BW3 * v9;
    }

    float d0[4], d1[4];
    #pragma unroll
    for (int j = 0; j < 4; ++j) {
        d0[j] = BW0 * hv[0][j] + BW1 * hv[1][j] + BW2 * hv[2][j] + BW3 * hv[3][j];
        d1[j] = BW0 * hv[2][j] + BW1 * hv[3][j] + BW2 * hv[4][j] + BW3 * hv[5][j];
    }

    // ---- 32 coalesced nontemporal float4 stores ----
    // out[t][b][cb*3+c][2hp+{0,1}][w4*4..+3]
    const size_t obase = (size_t)b * (12 * PLANE_OUT)
                       + (size_t)c * PLANE_OUT
                       + (size_t)(2 * hp) * W_OUT
                       + (size_t)(w4 * 4);
    #pragma unroll
    for (int t = 0; t < 4; ++t) {
        #pragma unroll
        for (int cb = 0; cb < 4; ++cb) {
            const float s = sc[t * 4 + cb];
            float* p0 = out + (size_t)t * TENSOR_STRIDE
                            + obase
                            + (size_t)cb * (3 * PLANE_OUT);
            float* p1 = p0 + W_OUT;
            f32x4 o0, o1;
            o0.x = d0[0] * s; o0.y = d0[1] * s; o0.z = d0[2] * s; o0.w = d0[3] * s;
            o1.x = d1[0] * s; o1.y = d1[1] * s; o1.z = d1[2] * s; o1.w = d1[3] * s;
            __builtin_nontemporal_store(o0, (f32x4*)p0);
            __builtin_nontemporal_store(o1, (f32x4*)p1);
        }
    }
}

extern "C" void kernel_launch(void* const* d_in, const int* in_sizes, int n_in,
                              void* d_out, int out_size, void* d_ws, size_t ws_size,
                              hipStream_t stream) {
    const float* img = (const float*)d_in[0];
    const float* gl  = (const float*)d_in[1];
    const float* gh  = (const float*)d_in[2];
    const float* fl  = (const float*)d_in[3];
    const float* fh  = (const float*)d_in[4];
    float* out = (float*)d_out;

    // 16*3*256*256 output pixels of D, 8 per thread (2 rows x 4 cols)
    const int threads = 256;
    const int blocks  = (16 * 3 * 256 * 256 / 8) / threads; // 1536
    qwt_fused_kernel<<<blocks, threads, 0, stream>>>(img, gl, gh, fl, fh, out);
}